// Round 4
// baseline (1076.170 us; speedup 1.0000x reference)
//
#include <hip/hip_runtime.h>
#include <math.h>

// ---------------- problem constants ----------------
#define NUM_CLASSES 80
#define TOPK 300
#define NTOT 10647             // 3*(169+676+2704)
#define L0END 507
#define L1END 2535

// level 0: 13x13 (mask 6,7,8), level 1: 26x26 (mask 3,4,5), level 2: 52x52 (mask 0,1,2)
__constant__ float ANCWf[3][3] = {{116.f,156.f,373.f},{30.f,62.f,59.f},{10.f,16.f,33.f}};
__constant__ float ANCHf[3][3] = {{90.f,198.f,326.f},{61.f,45.f,119.f},{13.f,30.f,23.f}};

// correctly-rounded f32 exp (f64 exp, rounded once)
__device__ __forceinline__ float expcr(float x) { return (float)exp((double)x); }
// numpy-style f32 sigmoid: op-by-op 1/(1+exp(-x)), each op f32 correctly rounded
__device__ __forceinline__ float sigf(float x) {
    float e = expcr(-x);
    return __fdiv_rn(1.0f, __fadd_rn(1.0f, e));
}

// locate anchor idx -> level geometry + channel-0 pointer (stride hw between channels)
__device__ __forceinline__ const float* locate(const float* f0, const float* f1, const float* f2,
                                               int img, int idx,
                                               int& level, int& hw, int& W, int& hrow, int& wcol, int& a) {
    int local, cell;
    const float* base;
    if (idx < L0END) {
        level = 0; local = idx; hw = 169; W = 13;
        base = f0 + (size_t)img * 43095;        // 255*169
    } else if (idx < L1END) {
        level = 1; local = idx - L0END; hw = 676; W = 26;
        base = f1 + (size_t)img * 172380;       // 255*676
    } else {
        level = 2; local = idx - L1END; hw = 2704; W = 52;
        base = f2 + (size_t)img * 689520;       // 255*2704
    }
    a = local / hw; cell = local - a * hw;
    hrow = cell / W; wcol = cell - hrow * W;
    return base + (size_t)(a * 85) * hw + cell;
}

// ---------------- kernel 1: numpy-f32 score per anchor ----------------
__global__ void score_kernel(const float* __restrict__ f0, const float* __restrict__ f1,
                             const float* __restrict__ f2, float* __restrict__ scores, int total) {
    int t = blockIdx.x * blockDim.x + threadIdx.x;
    if (t >= total) return;
    int img = t / NTOT;
    int idx = t - img * NTOT;
    int level, hw, W, hrow, wcol, a;
    const float* p = locate(f0, f1, f2, img, idx, level, hw, W, hrow, wcol, a);

    float obj = sigf(p[4 * hw]);
    // max over class logits; CR-f32 sigmoid is monotone nondecreasing, so
    // max_c sigf(v_c) == sigf(max_c v_c) BIT-EXACTLY.
    float mx = p[5 * hw];
    for (int c = 1; c < NUM_CLASSES; ++c) {
        float v = p[(5 + c) * hw];
        if (v > mx) mx = v;
    }
    float cls = sigf(mx);
    float s = __fmul_rn(obj, cls);
    scores[t] = (s >= 0.5f) ? s : 0.0f;
}

// ---------------- kernel 2: top-300 by selection (exact top_k semantics) ----------------
__global__ __launch_bounds__(1024) void topk_kernel(float* __restrict__ scores,
                                                    int* __restrict__ top_idx) {
    __shared__ float bv[1024];
    __shared__ int bi[1024];
    int img = blockIdx.x;
    int tid = threadIdx.x;
    float* sc = scores + (size_t)img * NTOT;

    for (int k = 0; k < TOPK; ++k) {
        float best = -2.0f; int besti = 0x7fffffff;
        for (int i = tid; i < NTOT; i += 1024) {
            float v = sc[i];
            if (v > best || (v == best && i < besti)) { best = v; besti = i; }
        }
        bv[tid] = best; bi[tid] = besti;
        __syncthreads();
        for (int s = 512; s > 0; s >>= 1) {
            if (tid < s) {
                float v2 = bv[tid + s]; int i2 = bi[tid + s];
                if (v2 > bv[tid] || (v2 == bv[tid] && i2 < bi[tid])) { bv[tid] = v2; bi[tid] = i2; }
            }
            __syncthreads();
        }
        if (tid == 0) {
            top_idx[img * TOPK + k] = bi[0];
            sc[bi[0]] = -1.0f;    // remove; all remaining scores >= 0
        }
        __syncthreads();
    }
}

// ---------------- kernel 3: per-image NMS + output (numpy-f32 op-by-op) ----------------
__global__ __launch_bounds__(320) void nms_kernel(const float* __restrict__ f0, const float* __restrict__ f1,
                                                  const float* __restrict__ f2,
                                                  const int* __restrict__ top_idx,
                                                  float* __restrict__ out) {
    __shared__ float bx[TOPK][4];   // output boxes (no class offset)
    __shared__ float bb[TOPK][4];   // class-offset boxes for IoU
    __shared__ float area[TOPK];
    __shared__ float sc[TOPK];      // thresholded score
    __shared__ float clsf[TOPK];
    __shared__ int keep[TOPK];

    int img = blockIdx.x;
    int tid = threadIdx.x;

    if (tid < TOPK) {
        int idx = top_idx[img * TOPK + tid];
        int level, hw, W, hrow, wcol, a;
        const float* p = locate(f0, f1, f2, img, idx, level, hw, W, hrow, wcol, a);

        // x = (sig + gx)/W ; y = (sig + gy)/H  (H==W per level)
        float x = __fdiv_rn(__fadd_rn(sigf(p[0]),      (float)wcol), (float)W);
        float y = __fdiv_rn(__fadd_rn(sigf(p[hw]),     (float)hrow), (float)W);
        float wd = __fdiv_rn(__fmul_rn(expcr(p[2 * hw]), ANCWf[level][a]), 416.0f);
        float ht = __fdiv_rn(__fmul_rn(expcr(p[3 * hw]), ANCHf[level][a]), 416.0f);
        float obj = sigf(p[4 * hw]);

        // literal reference: argmax over per-class f32 sigmoids (first max wins)
        float mx = sigf(p[5 * hw]);
        int cid = 0;
        for (int c = 1; c < NUM_CLASSES; ++c) {
            float v = sigf(p[(5 + c) * hw]);
            if (v > mx) { mx = v; cid = c; }
        }
        float score = __fmul_rn(obj, mx);
        if (!(score >= 0.5f)) score = 0.0f;

        // boxes = concat(xy - wh*0.5, xy + wh*0.5) * 416, op-by-op f32
        float hx = __fmul_rn(wd, 0.5f);
        float hy = __fmul_rn(ht, 0.5f);
        float x1 = __fmul_rn(__fsub_rn(x, hx), 416.0f);
        float y1 = __fmul_rn(__fsub_rn(y, hy), 416.0f);
        float x2 = __fmul_rn(__fadd_rn(x, hx), 416.0f);
        float y2 = __fmul_rn(__fadd_rn(y, hy), 416.0f);
        float off = __fmul_rn((float)cid, 832.0f);   // 2*INPUT

        bx[tid][0] = x1; bx[tid][1] = y1; bx[tid][2] = x2; bx[tid][3] = y2;
        float b0 = __fadd_rn(x1, off), b1 = __fadd_rn(y1, off);
        float b2 = __fadd_rn(x2, off), b3 = __fadd_rn(y2, off);
        bb[tid][0] = b0; bb[tid][1] = b1; bb[tid][2] = b2; bb[tid][3] = b3;
        area[tid] = __fmul_rn(__fsub_rn(b2, b0), __fsub_rn(b3, b1));
        sc[tid] = score;
        clsf[tid] = (float)cid;
        keep[tid] = 1;
    }
    __syncthreads();

    // greedy NMS, exact reference semantics, f32 op-by-op
    for (int i = 0; i < TOPK; ++i) {
        int ki = keep[i];
        if (ki && tid < TOPK && tid > i) {
            float ltx = fmaxf(bb[i][0], bb[tid][0]);
            float lty = fmaxf(bb[i][1], bb[tid][1]);
            float rbx = fminf(bb[i][2], bb[tid][2]);
            float rby = fminf(bb[i][3], bb[tid][3]);
            float wx = fmaxf(__fsub_rn(rbx, ltx), 0.0f);
            float wy = fmaxf(__fsub_rn(rby, lty), 0.0f);
            float inter = __fmul_rn(wx, wy);
            float denom = __fadd_rn(__fsub_rn(__fadd_rn(area[i], area[tid]), inter), 1e-6f);
            float iou = __fdiv_rn(inter, denom);
            if (iou > 0.3f) keep[tid] = 0;
        }
        __syncthreads();
    }

    if (tid < TOPK) {
        float m = (keep[tid] && (sc[tid] > 0.0f)) ? 1.0f : 0.0f;
        float* o = out + ((size_t)img * TOPK + tid) * 6;
        o[0] = __fmul_rn(bx[tid][0], m);
        o[1] = __fmul_rn(bx[tid][1], m);
        o[2] = __fmul_rn(bx[tid][2], m);
        o[3] = __fmul_rn(bx[tid][3], m);
        o[4] = __fmul_rn(sc[tid], m);
        o[5] = __fmul_rn(clsf[tid], m);
    }
}

extern "C" void kernel_launch(void* const* d_in, const int* in_sizes, int n_in,
                              void* d_out, int out_size, void* d_ws, size_t ws_size,
                              hipStream_t stream) {
    const float* f0 = (const float*)d_in[0];
    const float* f1 = (const float*)d_in[1];
    const float* f2 = (const float*)d_in[2];
    float* out = (float*)d_out;

    int B = in_sizes[0] / 43095;   // 255*13*13
    int total = B * NTOT;

    float* scores = (float*)d_ws;
    size_t scores_bytes = (size_t)B * NTOT * sizeof(float);
    int* top_idx = (int*)((char*)d_ws + scores_bytes);

    score_kernel<<<(total + 255) / 256, 256, 0, stream>>>(f0, f1, f2, scores, total);
    topk_kernel<<<B, 1024, 0, stream>>>(scores, top_idx);
    nms_kernel<<<B, 320, 0, stream>>>(f0, f1, f2, top_idx, out);
}